// Round 3
// baseline (1138.490 us; speedup 1.0000x reference)
//
#include <hip/hip_runtime.h>

// ---------------------------------------------------------------------------
// OptimEDM: denoised = softmax(-||x-y||^2 / 2s^2) @ y
// Round 3: QK dbuf + counted-vmcnt pipeline (stage 2 tiles ahead, vmcnt(8));
//          PV via pre-transposed yT, both operands gload_lds, BK=64, same
//          pipeline. Fallback to round-2 path if ws too small.
// ---------------------------------------------------------------------------

typedef __attribute__((ext_vector_type(4))) float f32x4;
typedef __attribute__((ext_vector_type(4))) unsigned short u16x4;
typedef __attribute__((ext_vector_type(8))) unsigned short u16x8;
typedef __attribute__((ext_vector_type(4))) unsigned int u32x4;
typedef __attribute__((ext_vector_type(8))) __bf16 bf16x8;

#define NREAL 50000
#define NP    50176   // 392 * 128
#define DD    3072
#define BB    512

#define WAIT8  asm volatile("s_waitcnt vmcnt(8)" ::: "memory")
#define WAIT0  asm volatile("s_waitcnt vmcnt(0)" ::: "memory")
#define BAR    __builtin_amdgcn_s_barrier()
#define SCHED0 __builtin_amdgcn_sched_barrier(0)

__device__ __forceinline__ unsigned short f32_bf16_rne(float f) {
  unsigned int u = __float_as_uint(f);
  unsigned int r = 0x7FFFu + ((u >> 16) & 1u);
  return (unsigned short)((u + r) >> 16);
}
__device__ __forceinline__ float bf16_f32(unsigned short h) {
  return __uint_as_float(((unsigned int)h) << 16);
}
__device__ __forceinline__ void gload16(const unsigned short* g, unsigned short* l) {
  __builtin_amdgcn_global_load_lds(
      (const __attribute__((address_space(1))) void*)g,
      (__attribute__((address_space(3))) void*)l, 16, 0, 0);
}

__global__ __launch_bounds__(256) void zero_kernel(f32x4* p) {
  p[(size_t)blockIdx.x * 256 + threadIdx.x] = (f32x4){0.f, 0.f, 0.f, 0.f};
}

__global__ __launch_bounds__(256) void prep_x_kernel(
    const float* __restrict__ x, const float* __restrict__ sigma,
    unsigned short* __restrict__ xhi, unsigned short* __restrict__ xlo,
    float* __restrict__ x2, float* __restrict__ inv2s2) {
  const int b = blockIdx.x, t = threadIdx.x;
  const f32x4* xr = (const f32x4*)(x + (size_t)b * DD);
  float ssq = 0.f;
#pragma unroll
  for (int i = 0; i < 3; ++i) {
    const int idx = i * 256 + t;
    f32x4 v = xr[idx];
    u16x4 h, l;
#pragma unroll
    for (int j = 0; j < 4; ++j) {
      float f = v[j];
      ssq += f * f;
      unsigned short hb = f32_bf16_rne(f);
      h[j] = hb;
      l[j] = f32_bf16_rne(f - bf16_f32(hb));
    }
    *(u16x4*)(xhi + (size_t)b * DD + idx * 4) = h;
    *(u16x4*)(xlo + (size_t)b * DD + idx * 4) = l;
  }
  __shared__ float red[4];
#pragma unroll
  for (int off = 32; off > 0; off >>= 1) ssq += __shfl_xor(ssq, off);
  if ((t & 63) == 0) red[t >> 6] = ssq;
  __syncthreads();
  if (t == 0) {
    x2[b] = red[0] + red[1] + red[2] + red[3];
    float s = sigma[b];
    inv2s2[b] = 1.0f / (2.0f * s * s);
  }
}

__global__ __launch_bounds__(256) void prep_y_kernel(
    const float* __restrict__ y, unsigned short* __restrict__ yhi,
    unsigned short* __restrict__ ylo, float* __restrict__ y2) {
  const int n = blockIdx.x, t = threadIdx.x;
  if (n >= NREAL) {
    u16x4 z = {0, 0, 0, 0};
#pragma unroll
    for (int i = 0; i < 3; ++i) {
      *(u16x4*)(yhi + (size_t)n * DD + (i * 256 + t) * 4) = z;
      *(u16x4*)(ylo + (size_t)n * DD + (i * 256 + t) * 4) = z;
    }
    if (t == 0) y2[n] = 0.f;
    return;
  }
  const f32x4* yr = (const f32x4*)(y + (size_t)n * DD);
  float ssq = 0.f;
#pragma unroll
  for (int i = 0; i < 3; ++i) {
    const int idx = i * 256 + t;
    f32x4 v = yr[idx];
    u16x4 h, l;
#pragma unroll
    for (int j = 0; j < 4; ++j) {
      float f = v[j];
      ssq += f * f;
      unsigned short hb = f32_bf16_rne(f);
      h[j] = hb;
      l[j] = f32_bf16_rne(f - bf16_f32(hb));
    }
    *(u16x4*)(yhi + (size_t)n * DD + idx * 4) = h;
    *(u16x4*)(ylo + (size_t)n * DD + idx * 4) = l;
  }
  __shared__ float red[4];
#pragma unroll
  for (int off = 32; off > 0; off >>= 1) ssq += __shfl_xor(ssq, off);
  if ((t & 63) == 0) red[t >> 6] = ssq;
  __syncthreads();
  if (t == 0) y2[n] = red[0] + red[1] + red[2] + red[3];
}

// 64x64 tile transpose: yhi[n][d] -> yT[d][n]
__global__ __launch_bounds__(256) void tr_kernel(
    const unsigned short* __restrict__ yhi, unsigned short* __restrict__ yT) {
  const int bn = blockIdx.x % 784, bd = blockIdx.x / 784;
  const int n0 = bn * 64, d0 = bd * 64;
  __shared__ unsigned short T[64][72];
  const int t = threadIdx.x;
  const int r = t >> 2, cc = (t & 3) * 16;
  u16x8 v0 = *(const u16x8*)(yhi + (size_t)(n0 + r) * DD + d0 + cc);
  u16x8 v1 = *(const u16x8*)(yhi + (size_t)(n0 + r) * DD + d0 + cc + 8);
  *(u16x8*)(&T[r][cc]) = v0;
  *(u16x8*)(&T[r][cc + 8]) = v1;
  __syncthreads();
  const int dr = t >> 2;
#pragma unroll
  for (int k = 0; k < 2; ++k) {
    const int nb = ((t & 3) * 2 + k) * 8;
    u16x8 o;
#pragma unroll
    for (int j = 0; j < 8; ++j) o[j] = T[nb + j][dr];
    *(u16x8*)(yT + (size_t)(d0 + dr) * NP + n0 + nb) = o;
  }
}

// ---------------------------------------------------------------------------
// QK: 128x128 tile, BK=32, dbuf, counted vmcnt(8), 2 tiles in flight.
// ---------------------------------------------------------------------------
__global__ __launch_bounds__(256) void qk_kernel(
    const unsigned short* __restrict__ yhi, const unsigned short* __restrict__ ylo,
    const unsigned short* __restrict__ xhi, const unsigned short* __restrict__ xlo,
    const float* __restrict__ x2, const float* __restrict__ inv2s2,
    const float* __restrict__ y2, float* __restrict__ S) {
  const int orig = blockIdx.x;
  const int virt = (orig & 7) * 196 + (orig >> 3);  // 1568 = 8*196
  const int mt = virt & 3, nt = virt >> 2;
  const int m0 = mt * 128, n0 = nt * 128;
  const int t = threadIdx.x;
  const int lane = t & 63, w = t >> 6;
  const int wrow = w >> 1, wcol = w & 1;
  const int l15 = lane & 15;

  __shared__ __align__(16) unsigned short L[2 * 4 * 4096];  // [buf][Ah,Al,Bh,Bl]

  f32x4 acc[4][4] = {};

  const int srow = t >> 2;
  const int schunk = ((t & 3) ^ ((t >> 3) & 3)) * 8;
  const int sdst = t * 8;
  const int cs8 = ((lane >> 4) ^ ((l15 >> 1) & 3)) * 8;

  const unsigned short* pAh0 = xhi + (size_t)(m0 + srow) * DD + schunk;
  const unsigned short* pAh1 = xhi + (size_t)(m0 + srow + 64) * DD + schunk;
  const unsigned short* pAl0 = xlo + (size_t)(m0 + srow) * DD + schunk;
  const unsigned short* pAl1 = xlo + (size_t)(m0 + srow + 64) * DD + schunk;
  const unsigned short* pBh0 = yhi + (size_t)(n0 + srow) * DD + schunk;
  const unsigned short* pBh1 = yhi + (size_t)(n0 + srow + 64) * DD + schunk;
  const unsigned short* pBl0 = ylo + (size_t)(n0 + srow) * DD + schunk;
  const unsigned short* pBl1 = ylo + (size_t)(n0 + srow + 64) * DD + schunk;

  auto STAGE = [&](int buf) {
    unsigned short* base = L + buf * 16384;
    gload16(pAh0, base + sdst);
    gload16(pAh1, base + sdst + 2048);
    gload16(pAl0, base + 4096 + sdst);
    gload16(pAl1, base + 4096 + sdst + 2048);
    gload16(pBh0, base + 8192 + sdst);
    gload16(pBh1, base + 8192 + sdst + 2048);
    gload16(pBl0, base + 12288 + sdst);
    gload16(pBl1, base + 12288 + sdst + 2048);
    pAh0 += 32; pAh1 += 32; pAl0 += 32; pAl1 += 32;
    pBh0 += 32; pBh1 += 32; pBl0 += 32; pBl1 += 32;
  };
  auto COMPUTE = [&](int buf) {
    const unsigned short* base = L + buf * 16384;
    bf16x8 ah[4], al[4], bh[4], bl[4];
#pragma unroll
    for (int mi = 0; mi < 4; ++mi) {
      const int off = (wrow * 64 + mi * 16 + l15) * 32 + cs8;
      ah[mi] = __builtin_bit_cast(bf16x8, *(const u16x8*)(base + off));
      al[mi] = __builtin_bit_cast(bf16x8, *(const u16x8*)(base + 4096 + off));
    }
#pragma unroll
    for (int ni = 0; ni < 4; ++ni) {
      const int off = (wcol * 64 + ni * 16 + l15) * 32 + cs8;
      bh[ni] = __builtin_bit_cast(bf16x8, *(const u16x8*)(base + 8192 + off));
      bl[ni] = __builtin_bit_cast(bf16x8, *(const u16x8*)(base + 12288 + off));
    }
    __builtin_amdgcn_s_setprio(1);
#pragma unroll
    for (int mi = 0; mi < 4; ++mi)
#pragma unroll
      for (int ni = 0; ni < 4; ++ni) {
        acc[mi][ni] = __builtin_amdgcn_mfma_f32_16x16x32_bf16(ah[mi], bh[ni], acc[mi][ni], 0, 0, 0);
        acc[mi][ni] = __builtin_amdgcn_mfma_f32_16x16x32_bf16(ah[mi], bl[ni], acc[mi][ni], 0, 0, 0);
        acc[mi][ni] = __builtin_amdgcn_mfma_f32_16x16x32_bf16(al[mi], bh[ni], acc[mi][ni], 0, 0, 0);
      }
    __builtin_amdgcn_s_setprio(0);
  };

  STAGE(0);
  STAGE(1);
  for (int ks = 0; ks < 94; ++ks) {
    WAIT8; BAR; SCHED0;
    COMPUTE(ks & 1);
    SCHED0; BAR; SCHED0;
    STAGE(ks & 1);
  }
  WAIT8; BAR; SCHED0;
  COMPUTE(0);
  WAIT0; BAR; SCHED0;
  COMPUTE(1);

#pragma unroll
  for (int ni = 0; ni < 4; ++ni) {
    int col = n0 + wcol * 64 + ni * 16 + l15;
    float yy = (col < NREAL) ? y2[col] : 0.f;
#pragma unroll
    for (int mi = 0; mi < 4; ++mi) {
#pragma unroll
      for (int i = 0; i < 4; ++i) {
        int row = m0 + wrow * 64 + mi * 16 + ((lane >> 4) * 4) + i;
        float v;
        if (col < NREAL) {
          float d2 = fmaxf(x2[row] + yy - 2.0f * acc[mi][ni][i], 0.0f);
          v = -d2 * inv2s2[row];
        } else {
          v = -3.0e38f;
        }
        S[(size_t)row * NP + col] = v;
      }
    }
  }
}

// ---------------------------------------------------------------------------
// softmax per row -> bf16 P
// ---------------------------------------------------------------------------
__global__ __launch_bounds__(256) void softmax_kernel(
    const float* __restrict__ S, unsigned short* __restrict__ P) {
  const int b = blockIdx.x, t = threadIdx.x;
  const f32x4* row = (const f32x4*)(S + (size_t)b * NP);
  __shared__ float red[4];

  float m = -3.4e38f;
#pragma unroll 4
  for (int i = 0; i < 49; ++i) {
    f32x4 v = row[i * 256 + t];
    m = fmaxf(m, fmaxf(fmaxf(v[0], v[1]), fmaxf(v[2], v[3])));
  }
#pragma unroll
  for (int off = 32; off > 0; off >>= 1) m = fmaxf(m, __shfl_xor(m, off));
  if ((t & 63) == 0) red[t >> 6] = m;
  __syncthreads();
  m = fmaxf(fmaxf(red[0], red[1]), fmaxf(red[2], red[3]));
  __syncthreads();

  float sum = 0.f;
#pragma unroll 4
  for (int i = 0; i < 49; ++i) {
    f32x4 v = row[i * 256 + t];
    sum += __expf(v[0] - m) + __expf(v[1] - m) + __expf(v[2] - m) + __expf(v[3] - m);
  }
#pragma unroll
  for (int off = 32; off > 0; off >>= 1) sum += __shfl_xor(sum, off);
  if ((t & 63) == 0) red[t >> 6] = sum;
  __syncthreads();
  const float inv = 1.0f / (red[0] + red[1] + red[2] + red[3]);

  unsigned short* pr = P + (size_t)b * NP;
#pragma unroll 4
  for (int i = 0; i < 49; ++i) {
    const int e = i * 256 + t;
    f32x4 v = row[e];
    u16x4 o;
    o[0] = f32_bf16_rne(__expf(v[0] - m) * inv);
    o[1] = f32_bf16_rne(__expf(v[1] - m) * inv);
    o[2] = f32_bf16_rne(__expf(v[2] - m) * inv);
    o[3] = f32_bf16_rne(__expf(v[3] - m) * inv);
    *(u16x4*)(pr + (size_t)e * 4) = o;
  }
}

// ---------------------------------------------------------------------------
// PV: out = P @ y via yT. 128(b)x128(d), BK=64 (2 k-slices), dbuf,
// counted vmcnt(8), split-K=8, fp32 atomics. grid 768 = 3*256.
// ---------------------------------------------------------------------------
__global__ __launch_bounds__(256) void pv_kernel(
    const unsigned short* __restrict__ yT, const unsigned short* __restrict__ P,
    float* __restrict__ out) {
  const int orig = blockIdx.x;
  const int virt = (orig & 7) * 96 + (orig >> 3);
  const int dt = virt % 24;          // dt innermost: P slice stays in L2
  const int mt = (virt / 24) & 3;
  const int sp = virt / 96;
  const int m0 = mt * 128, d0 = dt * 128;
  const int kbeg = sp * 6272;        // 98 steps of 64

  const int t = threadIdx.x, lane = t & 63, w = t >> 6;
  const int wrow = w >> 1, wcol = w & 1;
  const int l15 = lane & 15;

  __shared__ __align__(16) unsigned short L[2 * 4 * 4096];  // [buf][A0,A1,B0,B1]

  f32x4 acc[4][4] = {};

  const int srow = t >> 2;
  const int schunk = ((t & 3) ^ ((t >> 3) & 3)) * 8;
  const int sdst = t * 8;
  const int cs8 = ((lane >> 4) ^ ((l15 >> 1) & 3)) * 8;

  const unsigned short* pA00 = P + (size_t)(m0 + srow) * NP + kbeg + schunk;
  const unsigned short* pA01 = P + (size_t)(m0 + srow + 64) * NP + kbeg + schunk;
  const unsigned short* pA10 = pA00 + 32;
  const unsigned short* pA11 = pA01 + 32;
  const unsigned short* pB00 = yT + (size_t)(d0 + srow) * NP + kbeg + schunk;
  const unsigned short* pB01 = yT + (size_t)(d0 + srow + 64) * NP + kbeg + schunk;
  const unsigned short* pB10 = pB00 + 32;
  const unsigned short* pB11 = pB01 + 32;

  auto STAGE = [&](int buf) {
    unsigned short* base = L + buf * 16384;
    gload16(pA00, base + sdst);
    gload16(pA01, base + sdst + 2048);
    gload16(pA10, base + 4096 + sdst);
    gload16(pA11, base + 4096 + sdst + 2048);
    gload16(pB00, base + 8192 + sdst);
    gload16(pB01, base + 8192 + sdst + 2048);
    gload16(pB10, base + 12288 + sdst);
    gload16(pB11, base + 12288 + sdst + 2048);
    pA00 += 64; pA01 += 64; pA10 += 64; pA11 += 64;
    pB00 += 64; pB01 += 64; pB10 += 64; pB11 += 64;
  };
  auto COMPUTE = [&](int buf) {
    const unsigned short* base = L + buf * 16384;
#pragma unroll
    for (int s = 0; s < 2; ++s) {
      bf16x8 a[4], bv[4];
#pragma unroll
      for (int mi = 0; mi < 4; ++mi) {
        const int off = s * 4096 + (wrow * 64 + mi * 16 + l15) * 32 + cs8;
        a[mi] = __builtin_bit_cast(bf16x8, *(const u16x8*)(base + off));
      }
#pragma unroll
      for (int ni = 0; ni < 4; ++ni) {
        const int off = s * 4096 + (wcol * 64 + ni * 16 + l15) * 32 + cs8;
        bv[ni] = __builtin_bit_cast(bf16x8, *(const u16x8*)(base + 8192 + off));
      }
      __builtin_amdgcn_s_setprio(1);
#pragma unroll
      for (int mi = 0; mi < 4; ++mi)
#pragma unroll
        for (int ni = 0; ni < 4; ++ni)
          acc[mi][ni] = __builtin_amdgcn_mfma_f32_16x16x32_bf16(a[mi], bv[ni], acc[mi][ni], 0, 0, 0);
      __builtin_amdgcn_s_setprio(0);
    }
  };

  STAGE(0);
  STAGE(1);
  for (int ks = 0; ks < 96; ++ks) {
    WAIT8; BAR; SCHED0;
    COMPUTE(ks & 1);
    SCHED0; BAR; SCHED0;
    STAGE(ks & 1);
  }
  WAIT8; BAR; SCHED0;
  COMPUTE(0);
  WAIT0; BAR; SCHED0;
  COMPUTE(1);

#pragma unroll
  for (int mi = 0; mi < 4; ++mi)
#pragma unroll
    for (int ni = 0; ni < 4; ++ni)
#pragma unroll
      for (int i = 0; i < 4; ++i) {
        int row = m0 + wrow * 64 + mi * 16 + ((lane >> 4) * 4) + i;
        int col = d0 + wcol * 64 + ni * 16 + l15;
        unsafeAtomicAdd(out + (size_t)row * DD + col, acc[mi][ni][i]);
      }
}

// ===========================================================================
// Fallback (round-2 main path, known good): single-buffer QK, PV with
// in-kernel transpose of yhi.
// ===========================================================================
__global__ __launch_bounds__(256) void qk_fb_kernel(
    const unsigned short* __restrict__ yhi, const unsigned short* __restrict__ ylo,
    const unsigned short* __restrict__ xhi, const unsigned short* __restrict__ xlo,
    const float* __restrict__ x2, const float* __restrict__ inv2s2,
    const float* __restrict__ y2, float* __restrict__ S) {
  const int orig = blockIdx.x;
  const int virt = (orig & 7) * 196 + (orig >> 3);
  const int mt = virt & 3, nt = virt >> 2;
  const int m0 = mt * 128, n0 = nt * 128;
  const int t = threadIdx.x;
  const int lane = t & 63, w = t >> 6;
  const int wrow = w >> 1, wcol = w & 1;
  const int l15 = lane & 15;

  __shared__ __align__(16) unsigned short Ah[4096];
  __shared__ __align__(16) unsigned short Al[4096];
  __shared__ __align__(16) unsigned short Bh[4096];
  __shared__ __align__(16) unsigned short Bl[4096];

  f32x4 acc[4][4] = {};

  const int srow = t >> 2;
  const int schunk = (((t & 3) ^ ((t >> 3) & 3))) * 8;
  const int sdst = t * 8;
  const int cs8 = (((lane >> 4) ^ ((l15 >> 1) & 3))) * 8;

  auto STAGE = [&](int k0) {
#pragma unroll
    for (int r = 0; r < 2; ++r) {
      const int row = srow + r * 64;
      const size_t ga = (size_t)(m0 + row) * DD + k0 + schunk;
      const size_t gb = (size_t)(n0 + row) * DD + k0 + schunk;
      const int ld = sdst + r * 2048;
      gload16(xhi + ga, Ah + ld);
      gload16(xlo + ga, Al + ld);
      gload16(yhi + gb, Bh + ld);
      gload16(ylo + gb, Bl + ld);
    }
  };
  auto COMPUTE = [&]() {
    bf16x8 ah[4], al[4], bh[4], bl[4];
#pragma unroll
    for (int mi = 0; mi < 4; ++mi) {
      const int off = (wrow * 64 + mi * 16 + l15) * 32 + cs8;
      ah[mi] = __builtin_bit_cast(bf16x8, *(const u16x8*)(Ah + off));
      al[mi] = __builtin_bit_cast(bf16x8, *(const u16x8*)(Al + off));
    }
#pragma unroll
    for (int ni = 0; ni < 4; ++ni) {
      const int off = (wcol * 64 + ni * 16 + l15) * 32 + cs8;
      bh[ni] = __builtin_bit_cast(bf16x8, *(const u16x8*)(Bh + off));
      bl[ni] = __builtin_bit_cast(bf16x8, *(const u16x8*)(Bl + off));
    }
#pragma unroll
    for (int mi = 0; mi < 4; ++mi)
#pragma unroll
      for (int ni = 0; ni < 4; ++ni) {
        acc[mi][ni] = __builtin_amdgcn_mfma_f32_16x16x32_bf16(ah[mi], bh[ni], acc[mi][ni], 0, 0, 0);
        acc[mi][ni] = __builtin_amdgcn_mfma_f32_16x16x32_bf16(ah[mi], bl[ni], acc[mi][ni], 0, 0, 0);
        acc[mi][ni] = __builtin_amdgcn_mfma_f32_16x16x32_bf16(al[mi], bh[ni], acc[mi][ni], 0, 0, 0);
      }
  };

  STAGE(0);
  for (int ks = 0; ks < 96; ++ks) {
    __syncthreads();
    COMPUTE();
    __syncthreads();
    if (ks < 95) STAGE((ks + 1) * 32);
  }

#pragma unroll
  for (int ni = 0; ni < 4; ++ni) {
    int col = n0 + wcol * 64 + ni * 16 + l15;
    float yy = (col < NREAL) ? y2[col] : 0.f;
#pragma unroll
    for (int mi = 0; mi < 4; ++mi) {
#pragma unroll
      for (int i = 0; i < 4; ++i) {
        int row = m0 + wrow * 64 + mi * 16 + ((lane >> 4) * 4) + i;
        float v;
        if (col < NREAL) {
          float d2 = fmaxf(x2[row] + yy - 2.0f * acc[mi][ni][i], 0.0f);
          v = -d2 * inv2s2[row];
        } else {
          v = -3.0e38f;
        }
        S[(size_t)row * NP + col] = v;
      }
    }
  }
}

__global__ __launch_bounds__(256) void pv_fb_kernel(
    const unsigned short* __restrict__ yhi, const unsigned short* __restrict__ P,
    float* __restrict__ out) {
  const int orig = blockIdx.x;
  const int virt = (orig & 7) * 96 + (orig >> 3);
  const int mt = virt & 3;
  const int dt = (virt >> 2) % 24;
  const int sp = virt / 96;
  const int m0 = mt * 128, d0 = dt * 128;
  const int kbeg = sp * 6272;

  const int t = threadIdx.x, lane = t & 63, w = t >> 6;
  const int wrow = w >> 1, wcol = w & 1;
  const int l15 = lane & 15, kb = (lane >> 4) * 8;

  __shared__ __align__(16) unsigned short Ap[2][4096];
  __shared__ __align__(16) unsigned short Bt[128 * 40];

  f32x4 acc[4][4] = {};
  u16x4 rbh[4];

  const int srow = t >> 2;
  const int schunk = (((t & 3) ^ ((t >> 3) & 3))) * 8;
  const int sdst = t * 8;
  const int cs8 = (((lane >> 4) ^ ((l15 >> 1) & 3))) * 8;
  const int dcol = (t & 31) * 4;
  const int nr = (t >> 5) * 4;

  auto STAGEA = [&](int k0, int b) {
#pragma unroll
    for (int r = 0; r < 2; ++r)
      gload16(P + (size_t)(m0 + srow + r * 64) * NP + k0 + schunk,
              Ap[b] + sdst + r * 2048);
  };
  auto LOADB = [&](int k0) {
#pragma unroll
    for (int i = 0; i < 4; ++i)
      rbh[i] = *(const u16x4*)(yhi + (size_t)(k0 + nr + i) * DD + d0 + dcol);
  };
  auto STOREB = [&]() {
#pragma unroll
    for (int j = 0; j < 4; ++j) {
      u16x4 h;
#pragma unroll
      for (int i = 0; i < 4; ++i) h[i] = rbh[i][j];
      *(u16x4*)(Bt + (dcol + j) * 40 + nr) = h;
    }
  };
  auto COMPUTE = [&](int b) {
    bf16x8 a[4], bv[4];
#pragma unroll
    for (int mi = 0; mi < 4; ++mi)
      a[mi] = __builtin_bit_cast(bf16x8, *(const u16x8*)(Ap[b] + (wrow * 64 + mi * 16 + l15) * 32 + cs8));
#pragma unroll
    for (int ni = 0; ni < 4; ++ni)
      bv[ni] = __builtin_bit_cast(bf16x8, *(const u16x8*)(Bt + (wcol * 64 + ni * 16 + l15) * 40 + kb));
#pragma unroll
    for (int mi = 0; mi < 4; ++mi)
#pragma unroll
      for (int ni = 0; ni < 4; ++ni)
        acc[mi][ni] = __builtin_amdgcn_mfma_f32_16x16x32_bf16(a[mi], bv[ni], acc[mi][ni], 0, 0, 0);
  };

  STAGEA(kbeg, 0);
  LOADB(kbeg);
  int bf = 0;
  for (int ks = 0; ks < 196; ++ks) {
    __syncthreads();
    STOREB();
    if (ks < 195) { STAGEA(kbeg + (ks + 1) * 32, bf ^ 1); LOADB(kbeg + (ks + 1) * 32); }
    __syncthreads();
    COMPUTE(bf);
    bf ^= 1;
  }

#pragma unroll
  for (int mi = 0; mi < 4; ++mi)
#pragma unroll
    for (int ni = 0; ni < 4; ++ni)
#pragma unroll
      for (int i = 0; i < 4; ++i) {
        int row = m0 + wrow * 64 + mi * 16 + ((lane >> 4) * 4) + i;
        int col = d0 + wcol * 64 + ni * 16 + l15;
        unsafeAtomicAdd(out + (size_t)row * DD + col, acc[mi][ni][i]);
      }
}

// ---------------------------------------------------------------------------
extern "C" void kernel_launch(void* const* d_in, const int* in_sizes, int n_in,
                              void* d_out, int out_size, void* d_ws, size_t ws_size,
                              hipStream_t stream) {
  const float* x = (const float*)d_in[0];
  const float* sigma = (const float*)d_in[1];
  const float* y = (const float*)d_in[2];
  float* out = (float*)d_out;
  char* ws = (char*)d_ws;

  size_t off = 0;
  float* S = (float*)(ws + off);                      off += (size_t)BB * NP * 4;
  unsigned short* yhi = (unsigned short*)(ws + off);  off += (size_t)NP * DD * 2;
  unsigned short* ylo = (unsigned short*)(ws + off);  off += (size_t)NP * DD * 2;
  unsigned short* P = ylo;  // ylo dead after QK
  unsigned short* xhi = (unsigned short*)(ws + off);  off += (size_t)BB * DD * 2;
  unsigned short* xlo = (unsigned short*)(ws + off);  off += (size_t)BB * DD * 2;
  float* y2 = (float*)(ws + off);                     off += (size_t)NP * 4;
  float* x2 = (float*)(ws + off);                     off += 512 * 4;
  float* inv2s2 = (float*)(ws + off);                 off += 512 * 4;
  size_t off_fb = off;
  unsigned short* yT = (unsigned short*)(ws + off);   off += (size_t)DD * NP * 2;

  if (ws_size >= off) {
    // main path (with yT)
    zero_kernel<<<dim3(1536), dim3(256), 0, stream>>>((f32x4*)out);
    prep_x_kernel<<<dim3(512), dim3(256), 0, stream>>>(x, sigma, xhi, xlo, x2, inv2s2);
    prep_y_kernel<<<dim3(NP), dim3(256), 0, stream>>>(y, yhi, ylo, y2);
    tr_kernel<<<dim3(784 * 48), dim3(256), 0, stream>>>(yhi, yT);
    qk_kernel<<<dim3(1568), dim3(256), 0, stream>>>(yhi, ylo, xhi, xlo, x2, inv2s2, y2, S);
    softmax_kernel<<<dim3(512), dim3(256), 0, stream>>>(S, P);
    pv_kernel<<<dim3(768), dim3(256), 0, stream>>>(yT, P, out);
    return;
  }
  if (ws_size < off_fb) return;

  // fallback: round-2 path
  zero_kernel<<<dim3(1536), dim3(256), 0, stream>>>((f32x4*)out);
  prep_x_kernel<<<dim3(512), dim3(256), 0, stream>>>(x, sigma, xhi, xlo, x2, inv2s2);
  prep_y_kernel<<<dim3(NP), dim3(256), 0, stream>>>(y, yhi, ylo, y2);
  qk_fb_kernel<<<dim3(1568), dim3(256), 0, stream>>>(yhi, ylo, xhi, xlo, x2, inv2s2, y2, S);
  softmax_kernel<<<dim3(512), dim3(256), 0, stream>>>(S, P);
  pv_fb_kernel<<<dim3(768), dim3(256), 0, stream>>>(yhi, P, out);
}